// Round 14
// baseline (27.787 us; speedup 1.0000x reference)
//
#include <hip/hip_runtime.h>

#define NROW  524288
#define BLK   256
#define NKNN  10
#define YCOLS 44
#define OCOLS 24     // dxdt(2) + dvdt(2) + dudt(20)

#define TBL    128
#define T2_LO  (-2.0f)
#define T3_LO  (0.0f)
#define T_H    (1.0f / 8.0f)      // span 16 over 128 entries
#define T_INVH 8.0f
#define SROW   13                 // LDS floats per row (12 used): odd => conflict-free

typedef float f32x4 __attribute__((ext_vector_type(4)));

// exact scalar -> 16 -> 8 -> 1 MLP, weights via wave-uniform pointers (s_loads)
__device__ __forceinline__ float mlp_scalar_g(float s,
    const float* __restrict__ wa, const float* __restrict__ ba,
    const float* __restrict__ wb, const float* __restrict__ bb,
    const float* __restrict__ wc, const float* __restrict__ bc) {
    float h[16];
#pragma unroll
    for (int j = 0; j < 16; ++j)
        h[j] = fmaxf(fmaf(s, wa[j], ba[j]), 0.0f);
    float g[8];
#pragma unroll
    for (int k = 0; k < 8; ++k) g[k] = bb[k];
#pragma unroll
    for (int j = 0; j < 16; ++j) {
        float hj = h[j];
#pragma unroll
        for (int k = 0; k < 8; ++k)
            g[k] = fmaf(hj, wb[j * 8 + k], g[k]);
    }
    float o = bc[0];
#pragma unroll
    for (int k = 0; k < 8; ++k)
        o = fmaf(fmaxf(g[k], 0.0f), wc[k], o);
    return o;
}

__device__ __forceinline__ float tbl_eval(const float* __restrict__ T, float s, float lo) {
    float u = (s - lo) * T_INVH;
    u = fminf(fmaxf(u, 0.0f), (float)TBL - 1.001f);
    int i = (int)u;
    float f = u - (float)i;
    float va = T[i];
    float vb = T[i + 1];
    return fmaf(f, vb - va, va);
}

// ---- single fused kernel: 1 tile/block, half-row LDS staging, 8 blocks/CU ----
__global__ __launch_bounds__(BLK) void odefunc_kernel(
    const float* __restrict__ y,
    const float* __restrict__ w1a, const float* __restrict__ b1a,
    const float* __restrict__ w1b, const float* __restrict__ b1b,
    const float* __restrict__ w2a, const float* __restrict__ b2a,
    const float* __restrict__ w2b, const float* __restrict__ b2b,
    const float* __restrict__ w2c, const float* __restrict__ b2c,
    const float* __restrict__ w3a, const float* __restrict__ b3a,
    const float* __restrict__ w3b, const float* __restrict__ b3b,
    const float* __restrict__ w3c, const float* __restrict__ b3c,
    float* __restrict__ out)
{
    __shared__ float Sf[BLK * SROW];  // 13.3 KB (half-row staging, reused A->B->result)
    __shared__ float T2v[TBL];        // 0.5 KB
    __shared__ float T3v[TBL];        // 0.5 KB
    __shared__ float o100s;

    const int t    = threadIdx.x;
    const int w    = t >> 6;
    const int lane = t & 63;

    const f32x4* yb = reinterpret_cast<const f32x4*>(y)
                    + (size_t)blockIdx.x * BLK * (YCOLS / 4);
    f32x4* ob = reinterpret_cast<f32x4*>(out)
              + (size_t)blockIdx.x * BLK * (OCOLS / 4);

    // 1: issue ALL 6 chunk loads up front (3 for half A: cc 0..2; 3 for half B: cc 3..5)
    f32x4 ldA[3], ldB[3];
    int rrA[3], ccA[3], rrB[3], ccB[3];
#pragma unroll
    for (int i = 0; i < 3; ++i) {
        int j  = lane + i * 64;        // 0..191 compact over (row, halfchunk)
        int rr = j / 3;
        int cc = j - rr * 3;
        rrA[i] = rr; ccA[i] = cc;
        ldA[i] = yb[(64 * w + rr) * 11 + cc];
    }
#pragma unroll
    for (int i = 0; i < 3; ++i) {
        int j  = lane + i * 64;
        int rr = j / 3;
        int cc = j - rr * 3;
        rrB[i] = rr; ccB[i] = cc;
        ldB[i] = yb[(64 * w + rr) * 11 + (cc + 3)];
    }

    // 2: tabulate (ONE exact eval per thread; wave-uniform split)
    if (t < TBL) {
        T2v[t] = mlp_scalar_g(T2_LO + (float)t * T_H, w2a, b2a, w2b, b2b, w2c, b2c);
        if (t == 0)
            o100s = mlp_scalar_g(100.0f, w2a, b2a, w2b, b2b, w2c, b2c);
    } else {
        int i3 = t - TBL;
        T3v[i3] = mlp_scalar_g(T3_LO + (float)i3 * T_H, w3a, b3a, w3b, b3b, w3c, b3c);
    }

    // 3: the ONLY block barrier
    __syncthreads();
    const float o100 = o100s;

    // 4: stage half A (x0,x1,vx,vy, n0..n3) into wave-own stride-13 rows
#pragma unroll
    for (int i = 0; i < 3; ++i) {
        int base = (64 * w + rrA[i]) * SROW + 4 * ccA[i];
        Sf[base + 0] = ldA[i].x;
        Sf[base + 1] = ldA[i].y;
        Sf[base + 2] = ldA[i].z;
        Sf[base + 3] = ldA[i].w;
    }
    __builtin_amdgcn_wave_barrier();

    // 5: read own row (half A) and compute f1 + f2 + f3[n0..3]
    float* R = Sf + t * SROW;
    float x0 = R[0], x1 = R[1], vx = R[2], vy = R[3];
    float uA[8];
#pragma unroll
    for (int m = 0; m < 8; ++m) uA[m] = R[4 + m];
    __builtin_amdgcn_wave_barrier();   // all A-reads precede B-overwrites (wave lockstep)

    // f1: door-direction MLP (4 -> 8 -> 2)
    float dxm = 5.6f - x0;
    float dym = 0.0f - x1;
    float inv = rsqrtf(fmaf(dxm, dxm, dym * dym));
    float in1[4] = { dxm * inv, dym * inv, vx, vy };
    float h1[8];
#pragma unroll
    for (int j = 0; j < 8; ++j) {
        float s = b1a[j];
#pragma unroll
        for (int k = 0; k < 4; ++k)
            s = fmaf(in1[k], w1a[k * 8 + j], s);
        h1[j] = fmaxf(s, 0.0f);
    }
    float f1x = b1b[0];
    float f1y = b1b[1];
#pragma unroll
    for (int j = 0; j < 8; ++j) {
        f1x = fmaf(h1[j], w1b[j * 2 + 0], f1x);
        f1y = fmaf(h1[j], w1b[j * 2 + 1], f1y);
    }

    // f2: wall MLP via table
    bool corridor = (x1 < 1.0f) && (x1 > -1.0f);
    float o0 = tbl_eval(T2v, x0 + 5.0f, T2_LO);
    float o1 = tbl_eval(T2v, x1 + 5.0f, T2_LO);
    float o2 = tbl_eval(T2v, 5.0f - x1, T2_LO);
    float o3 = corridor ? o100 : tbl_eval(T2v, 5.0f - x0, T2_LO);
    float f2x = o0 - o3;
    float f2y = o1 - o2;

    // f3 partial: n = 0..3
    float f3x = 0.0f, f3y = 0.0f;
#pragma unroll
    for (int n = 0; n < 4; ++n) {
        float uxn = uA[2 * n + 0];
        float uyn = uA[2 * n + 1];
        float s2  = fmaf(uxn, uxn, uyn * uyn);
        float idn = rsqrtf(s2);
        float d   = s2 * idn;
        float m   = tbl_eval(T3v, d, T3_LO);
        float c   = m * idn;
        f3x = fmaf(-c, uxn, f3x);
        f3y = fmaf(-c, uyn, f3y);
    }

    // 6: stage half B (n4..n9) over the same row floats [0..11]
#pragma unroll
    for (int i = 0; i < 3; ++i) {
        int base = (64 * w + rrB[i]) * SROW + 4 * ccB[i];
        Sf[base + 0] = ldB[i].x;
        Sf[base + 1] = ldB[i].y;
        Sf[base + 2] = ldB[i].z;
        Sf[base + 3] = ldB[i].w;
    }
    __builtin_amdgcn_wave_barrier();

    float uB[12];
#pragma unroll
    for (int m = 0; m < 12; ++m) uB[m] = R[m];
    __builtin_amdgcn_wave_barrier();   // all B-reads precede result writes

    // f3 rest: n = 4..9
#pragma unroll
    for (int n = 0; n < 6; ++n) {
        float uxn = uB[2 * n + 0];
        float uyn = uB[2 * n + 1];
        float s2  = fmaf(uxn, uxn, uyn * uyn);
        float idn = rsqrtf(s2);
        float d   = s2 * idn;
        float m   = tbl_eval(T3v, d, T3_LO);
        float c   = m * idn;
        f3x = fmaf(-c, uxn, f3x);
        f3y = fmaf(-c, uyn, f3y);
    }

    // 7: result into own row
    bool dead = (x0 > 5.0f);
    const float k80 = 1.0f / 80.0f;
    R[0] = dead ? 0.0f : vx;
    R[1] = dead ? 0.0f : vy;
    R[2] = dead ? 0.0f : (f1x + f2x + f3x) * k80;
    R[3] = dead ? 0.0f : (f1y + f2y + f3y) * k80;
    __builtin_amdgcn_wave_barrier();

    // 8: compact nontemporal store (cc==0 lanes gather, rest write zeros)
#pragma unroll
    for (int i = 0; i < 6; ++i) {
        int j  = lane + i * 64;
        int rr = j / 6;
        int cc = j - rr * 6;
        f32x4 v = (f32x4)(0.0f);
        if (cc == 0) {
            const float* Rr = Sf + (64 * w + rr) * SROW;
            v.x = Rr[0]; v.y = Rr[1]; v.z = Rr[2]; v.w = Rr[3];
        }
        __builtin_nontemporal_store(v, &ob[384 * w + j]);
    }
}

extern "C" void kernel_launch(void* const* d_in, const int* in_sizes, int n_in,
                              void* d_out, int out_size, void* d_ws, size_t ws_size,
                              hipStream_t stream) {
    int iy = 1;
    for (int i = 0; i < n_in; ++i) {
        if (in_sizes[i] == NROW * YCOLS) { iy = i; break; }
    }
    const float* y   = (const float*)d_in[iy];
    const float* w1a = (const float*)d_in[iy + 1];
    const float* b1a = (const float*)d_in[iy + 2];
    const float* w1b = (const float*)d_in[iy + 3];
    const float* b1b = (const float*)d_in[iy + 4];
    const float* w2a = (const float*)d_in[iy + 5];
    const float* b2a = (const float*)d_in[iy + 6];
    const float* w2b = (const float*)d_in[iy + 7];
    const float* b2b = (const float*)d_in[iy + 8];
    const float* w2c = (const float*)d_in[iy + 9];
    const float* b2c = (const float*)d_in[iy + 10];
    const float* w3a = (const float*)d_in[iy + 11];
    const float* b3a = (const float*)d_in[iy + 12];
    const float* w3b = (const float*)d_in[iy + 13];
    const float* b3b = (const float*)d_in[iy + 14];
    const float* w3c = (const float*)d_in[iy + 15];
    const float* b3c = (const float*)d_in[iy + 16];
    float* out = (float*)d_out;

    hipLaunchKernelGGL(odefunc_kernel, dim3(NROW / BLK), dim3(BLK), 0, stream,
                       y, w1a, b1a, w1b, b1b,
                       w2a, b2a, w2b, b2b, w2c, b2c,
                       w3a, b3a, w3b, b3b, w3c, b3c, out);
}

// Round 15
// 25.873 us; speedup vs baseline: 1.0740x; 1.0740x over previous
//
#include <hip/hip_runtime.h>

#define NROW  524288
#define BLK   256
#define TPB   2                   // tiles per block
#define NKNN  10
#define YCOLS 44
#define OCOLS 24     // dxdt(2) + dvdt(2) + dudt(20)

#define TBL    128
#define T2_LO  (-2.0f)
#define T3_LO  (0.0f)
#define T_H    (1.0f / 8.0f)      // span 16 over 128 entries
#define T_INVH 8.0f
#define SROW   25                 // LDS floats per row: odd => bank-conflict-free

typedef float f32x4 __attribute__((ext_vector_type(4)));

// exact scalar -> 16 -> 8 -> 1 MLP, weights via wave-uniform pointers (s_loads)
__device__ __forceinline__ float mlp_scalar_g(float s,
    const float* __restrict__ wa, const float* __restrict__ ba,
    const float* __restrict__ wb, const float* __restrict__ bb,
    const float* __restrict__ wc, const float* __restrict__ bc) {
    float h[16];
#pragma unroll
    for (int j = 0; j < 16; ++j)
        h[j] = fmaxf(fmaf(s, wa[j], ba[j]), 0.0f);
    float g[8];
#pragma unroll
    for (int k = 0; k < 8; ++k) g[k] = bb[k];
#pragma unroll
    for (int j = 0; j < 16; ++j) {
        float hj = h[j];
#pragma unroll
        for (int k = 0; k < 8; ++k)
            g[k] = fmaf(hj, wb[j * 8 + k], g[k]);
    }
    float o = bc[0];
#pragma unroll
    for (int k = 0; k < 8; ++k)
        o = fmaf(fmaxf(g[k], 0.0f), wc[k], o);
    return o;
}

__device__ __forceinline__ float tbl_eval(const float* __restrict__ T, float s, float lo) {
    float u = (s - lo) * T_INVH;
    u = fminf(fmaxf(u, 0.0f), (float)TBL - 1.001f);
    int i = (int)u;
    float f = u - (float)i;
    float va = T[i];
    float vb = T[i + 1];
    return fmaf(f, vb - va, va);
}

// wave-compact load of one tile's 6 float4 per thread
__device__ __forceinline__ void load_tile(const f32x4* __restrict__ yb,
                                          int w, int lane, f32x4 ld[6]) {
#pragma unroll
    for (int i = 0; i < 6; ++i) {
        int j  = lane + i * 64;            // wave-compact index 0..383
        int rr = j / 6;
        int cc = j - rr * 6;
        ld[i]  = yb[(64 * w + rr) * 11 + cc];
    }
}

// deposit into stride-25 float rows (near-conflict-free b32 writes)
__device__ __forceinline__ void stage_tile(float* __restrict__ Sf,
                                           int w, int lane, const f32x4 ld[6]) {
#pragma unroll
    for (int i = 0; i < 6; ++i) {
        int j  = lane + i * 64;
        int rr = j / 6;
        int cc = j - rr * 6;
        int base = (64 * w + rr) * SROW + 4 * cc;
        Sf[base + 0] = ld[i].x;
        Sf[base + 1] = ld[i].y;
        Sf[base + 2] = ld[i].z;
        Sf[base + 3] = ld[i].w;
    }
}

// thread t computes its row; writes 4-float result back at its row base
__device__ __forceinline__ void compute_row(float* __restrict__ Sf, int t,
    const float* __restrict__ T2v, const float* __restrict__ T3v, float o100,
    const float* __restrict__ w1a, const float* __restrict__ b1a,
    const float* __restrict__ w1b, const float* __restrict__ b1b)
{
    float* R = Sf + t * SROW;              // base bank = 25t mod 32: all lanes distinct
    float x0 = R[0], x1 = R[1], vx = R[2], vy = R[3];
    float us[2 * NKNN];
#pragma unroll
    for (int m = 0; m < 2 * NKNN; ++m)
        us[m] = R[4 + m];

    // f1: door-direction MLP (4 -> 8 -> 2)
    float dx = 5.6f - x0;
    float dy = 0.0f - x1;
    float inv = rsqrtf(fmaf(dx, dx, dy * dy));
    float in1[4] = { dx * inv, dy * inv, vx, vy };
    float h1[8];
#pragma unroll
    for (int j = 0; j < 8; ++j) {
        float s = b1a[j];
#pragma unroll
        for (int k = 0; k < 4; ++k)
            s = fmaf(in1[k], w1a[k * 8 + j], s);
        h1[j] = fmaxf(s, 0.0f);
    }
    float f1x = b1b[0];
    float f1y = b1b[1];
#pragma unroll
    for (int j = 0; j < 8; ++j) {
        f1x = fmaf(h1[j], w1b[j * 2 + 0], f1x);
        f1y = fmaf(h1[j], w1b[j * 2 + 1], f1y);
    }

    // f2: wall MLP via table
    bool corridor = (x1 < 1.0f) && (x1 > -1.0f);
    float o0 = tbl_eval(T2v, x0 + 5.0f, T2_LO);
    float o1 = tbl_eval(T2v, x1 + 5.0f, T2_LO);
    float o2 = tbl_eval(T2v, 5.0f - x1, T2_LO);
    float o3 = corridor ? o100 : tbl_eval(T2v, 5.0f - x0, T2_LO);
    float f2x = o0 - o3;
    float f2y = o1 - o2;

    // f3: neighbor MLP via table
    float f3x = 0.0f, f3y = 0.0f;
#pragma unroll
    for (int n = 0; n < NKNN; ++n) {
        float uxn = us[2 * n + 0];
        float uyn = us[2 * n + 1];
        float s2  = fmaf(uxn, uxn, uyn * uyn);
        float idn = rsqrtf(s2);
        float d   = s2 * idn;     // = sqrt(s2)
        float m   = tbl_eval(T3v, d, T3_LO);
        float c   = m * idn;
        f3x = fmaf(-c, uxn, f3x);
        f3y = fmaf(-c, uyn, f3y);
    }

    bool dead = (x0 > 5.0f);
    const float k80 = 1.0f / 80.0f;
    R[0] = dead ? 0.0f : vx;
    R[1] = dead ? 0.0f : vy;
    R[2] = dead ? 0.0f : (f1x + f2x + f3x) * k80;
    R[3] = dead ? 0.0f : (f1y + f2y + f3y) * k80;
}

// compact nontemporal store; only cc==0 lanes read LDS (predicated), rest write zeros
__device__ __forceinline__ void store_tile(f32x4* __restrict__ ob,
                                           const float* __restrict__ Sf,
                                           int w, int lane) {
#pragma unroll
    for (int i = 0; i < 6; ++i) {
        int j  = lane + i * 64;
        int rr = j / 6;
        int cc = j - rr * 6;
        f32x4 v = (f32x4)(0.0f);
        if (cc == 0) {
            const float* R = Sf + (64 * w + rr) * SROW;
            v.x = R[0]; v.y = R[1]; v.z = R[2]; v.w = R[3];
        }
        __builtin_nontemporal_store(v, &ob[384 * w + j]);
    }
}

// ---- single fused kernel: 2 tiles/block, stride-25 LDS, 1-eval tables ----
__global__ __launch_bounds__(BLK) void odefunc_kernel(
    const float* __restrict__ y,
    const float* __restrict__ w1a, const float* __restrict__ b1a,
    const float* __restrict__ w1b, const float* __restrict__ b1b,
    const float* __restrict__ w2a, const float* __restrict__ b2a,
    const float* __restrict__ w2b, const float* __restrict__ b2b,
    const float* __restrict__ w2c, const float* __restrict__ b2c,
    const float* __restrict__ w3a, const float* __restrict__ b3a,
    const float* __restrict__ w3b, const float* __restrict__ b3b,
    const float* __restrict__ w3c, const float* __restrict__ b3c,
    float* __restrict__ out)
{
    __shared__ float Sf[BLK * SROW];  // 25.6 KB staging, reused across tiles
    __shared__ float T2v[TBL];        // 0.5 KB
    __shared__ float T3v[TBL];        // 0.5 KB
    __shared__ float o100s;

    const int t    = threadIdx.x;
    const int w    = t >> 6;
    const int lane = t & 63;

    const f32x4* yb0 = reinterpret_cast<const f32x4*>(y)
                     + (size_t)blockIdx.x * TPB * BLK * (YCOLS / 4);
    const f32x4* yb1 = yb0 + BLK * (YCOLS / 4);
    f32x4* ob0 = reinterpret_cast<f32x4*>(out)
               + (size_t)blockIdx.x * TPB * BLK * (OCOLS / 4);
    f32x4* ob1 = ob0 + BLK * (OCOLS / 4);

    // 1: issue tile-0 loads
    f32x4 ld0[6];
    load_tile(yb0, w, lane, ld0);

    // 2: tabulate (ONE exact eval per thread; branch is wave-uniform)
    if (t < TBL) {
        T2v[t] = mlp_scalar_g(T2_LO + (float)t * T_H, w2a, b2a, w2b, b2b, w2c, b2c);
        if (t == 0)
            o100s = mlp_scalar_g(100.0f, w2a, b2a, w2b, b2b, w2c, b2c);
    } else {
        int i3 = t - TBL;
        T3v[i3] = mlp_scalar_g(T3_LO + (float)i3 * T_H, w3a, b3a, w3b, b3b, w3c, b3c);
    }

    // 3: the ONLY block barrier
    __syncthreads();
    const float o100 = o100s;

    // 4: stage tile-0 (wave-local)
    stage_tile(Sf, w, lane, ld0);
    __builtin_amdgcn_wave_barrier();

    // 5: prefetch tile-1 (hides under tile-0 compute+store)
    f32x4 ld1[6];
    load_tile(yb1, w, lane, ld1);

    // 6: compute tile-0, stream out
    compute_row(Sf, t, T2v, T3v, o100, w1a, b1a, w1b, b1b);
    __builtin_amdgcn_wave_barrier();
    store_tile(ob0, Sf, w, lane);
    __builtin_amdgcn_wave_barrier();

    // 7: stage tile-1
    stage_tile(Sf, w, lane, ld1);
    __builtin_amdgcn_wave_barrier();

    // 8: compute tile-1, stream out
    compute_row(Sf, t, T2v, T3v, o100, w1a, b1a, w1b, b1b);
    __builtin_amdgcn_wave_barrier();
    store_tile(ob1, Sf, w, lane);
}

extern "C" void kernel_launch(void* const* d_in, const int* in_sizes, int n_in,
                              void* d_out, int out_size, void* d_ws, size_t ws_size,
                              hipStream_t stream) {
    int iy = 1;
    for (int i = 0; i < n_in; ++i) {
        if (in_sizes[i] == NROW * YCOLS) { iy = i; break; }
    }
    const float* y   = (const float*)d_in[iy];
    const float* w1a = (const float*)d_in[iy + 1];
    const float* b1a = (const float*)d_in[iy + 2];
    const float* w1b = (const float*)d_in[iy + 3];
    const float* b1b = (const float*)d_in[iy + 4];
    const float* w2a = (const float*)d_in[iy + 5];
    const float* b2a = (const float*)d_in[iy + 6];
    const float* w2b = (const float*)d_in[iy + 7];
    const float* b2b = (const float*)d_in[iy + 8];
    const float* w2c = (const float*)d_in[iy + 9];
    const float* b2c = (const float*)d_in[iy + 10];
    const float* w3a = (const float*)d_in[iy + 11];
    const float* b3a = (const float*)d_in[iy + 12];
    const float* w3b = (const float*)d_in[iy + 13];
    const float* b3b = (const float*)d_in[iy + 14];
    const float* w3c = (const float*)d_in[iy + 15];
    const float* b3c = (const float*)d_in[iy + 16];
    float* out = (float*)d_out;

    hipLaunchKernelGGL(odefunc_kernel, dim3(NROW / (BLK * TPB)), dim3(BLK), 0, stream,
                       y, w1a, b1a, w1b, b1b,
                       w2a, b2a, w2b, b2b, w2c, b2c,
                       w3a, b3a, w3b, b3b, w3c, b3c, out);
}